// Round 8
// baseline (2014.840 us; speedup 1.0000x reference)
//
#include <hip/hip_runtime.h>
#include <hip/hip_bf16.h>

// MPNN: N=100000 nodes, E=1600000 edges, D=128, L=4, G=64.
// All GEMM-shaped work on MFMA bf16 (fp32 accumulate), fp32 residual stream h.
//   prep: fold BN into W2 (both MLPs), transpose all B-matrices to [n][k] bf16,
//         counting-sort edges by dst, per-64-edge-tile segment-start bitmasks.
//   per layer:
//     edge_kernel (2 tiles/block, double-buffered pipeline):
//         t = relu(P[dst]+Q[src]+ea@W1c+b1) -> bf16 LDS (Tl[buf])
//         m = relu(t@W2f+b2f)   (MFMA) -> written back into Tl[buf]
//         mask-driven segmented reduce -> aggr (256-B-contiguous nt stores)
//     upd_kernel:  u1 = relu([h|aggr]@U1+ub1) (MFMA K=256) -> bf16 LDS overlay
//                  h += relu(u1@U2f+uB2f)     (MFMA K=128), in-place
//                  + fused next-layer P/Q = h_new @ W1ab (via LDS h_new tile)
// Cache policy: P/Q gathers use normal (caching) loads; all streaming traffic
// (ea/dst/src staging, aggr stores, sort outputs) is non-temporal so the
// 2x25.6MB P/Q arrays stay L3-resident. NOTE: __builtin_nontemporal_* needs
// native ext-vector types, not HIP_vector_type float4 -> use floatx4.

#define EPSBN 1e-5f
#define TS 136   // bf16 elems per LDS row for 128-wide tiles (272 B = 17*16 B)
#define AS 264   // bf16 elems per LDS row for 256-wide tiles (528 B = 33*16 B)

typedef __bf16 bf16x8 __attribute__((ext_vector_type(8)));
typedef float floatx4 __attribute__((ext_vector_type(4)));

static __device__ __forceinline__ unsigned short f2b(float f) {
  union { float f; unsigned u; } v; v.f = f;
  unsigned u = v.u;
  return (unsigned short)((u + 0x7fffu + ((u >> 16) & 1u)) >> 16);  // RNE
}
static __device__ __forceinline__ unsigned pk2(float lo, float hi) {
  union { __hip_bfloat162 h; unsigned u; } v;
  v.h = __float22bfloat162_rn(make_float2(lo, hi));  // v_cvt_pk_bf16_f32
  return v.u;
}
static __device__ __forceinline__ float ubits(unsigned u) {
  union { unsigned u; float f; } v; v.u = u; return v.f;
}

// ---------------- fold BN into second linear, write transposed bf16 ----------------
__global__ __launch_bounds__(128) void fold_kernel(
    const float* __restrict__ mw2, const float* __restrict__ mb2,
    const float* __restrict__ mg, const float* __restrict__ mb,
    const float* __restrict__ mm, const float* __restrict__ mv,
    const float* __restrict__ uw2, const float* __restrict__ ub2,
    const float* __restrict__ ug, const float* __restrict__ ub,
    const float* __restrict__ um, const float* __restrict__ uv,
    unsigned short* __restrict__ mW2fT, float* __restrict__ mB2f,
    unsigned short* __restrict__ uW2fT, float* __restrict__ uB2f) {
  int l = blockIdx.x & 3;
  bool isu = blockIdx.x >= 4;
  const float* W2 = (isu ? uw2 : mw2) + (size_t)l * 128 * 128;
  const float* b2 = (isu ? ub2 : mb2) + l * 128;
  const float* gg = (isu ? ug : mg) + l * 128;
  const float* bb = (isu ? ub : mb) + l * 128;
  const float* mn = (isu ? um : mm) + l * 128;
  const float* vr = (isu ? uv : mv) + l * 128;
  unsigned short* WfT = (isu ? uW2fT : mW2fT) + (size_t)l * 128 * 128;
  float* Bf = (isu ? uB2f : mB2f) + l * 128;
  __shared__ float a[128], c[128];
  int d = threadIdx.x;
  float ad = gg[d] * rsqrtf(vr[d] + EPSBN);
  a[d] = ad;
  c[d] = bb[d] - mn[d] * ad;
  __syncthreads();
  float acc = b2[d];
  for (int k = 0; k < 128; ++k) {
    float w = W2[k * 128 + d];
    WfT[(size_t)d * 128 + k] = f2b(a[k] * w);  // [n][k] bf16
    acc = fmaf(c[k], w, acc);
  }
  Bf[d] = acc;
}

// ---------------- transpose W1ab / U1 to [n][k] bf16 ----------------
__global__ __launch_bounds__(256) void transp_kernel(
    const float* __restrict__ mw1, const float* __restrict__ uw1,
    unsigned short* __restrict__ W1abT, unsigned short* __restrict__ U1T) {
  int l = blockIdx.x & 3;
  bool isu = blockIdx.x >= 4;
  int tid = threadIdx.x;
  if (!isu) {
    const float* W = mw1 + (size_t)l * 260 * 128;
    unsigned short* T = W1abT + (size_t)l * 256 * 128;
    for (int i = tid; i < 256 * 128; i += 256) {
      int n = i >> 7, k = i & 127;
      float v = (n < 128) ? W[(size_t)k * 128 + n] : W[(size_t)(128 + k) * 128 + (n - 128)];
      T[i] = f2b(v);
    }
  } else {
    const float* W = uw1 + (size_t)l * 256 * 128;
    unsigned short* T = U1T + (size_t)l * 128 * 256;
    for (int i = tid; i < 128 * 256; i += 256) {
      int n = i >> 8, k = i & 255;
      T[i] = f2b(W[(size_t)k * 128 + n]);
    }
  }
}

// ---------------- input projection ----------------
__global__ __launch_bounds__(256) void lin_in_kernel(
    const float* __restrict__ x, const float* __restrict__ pos,
    const float* __restrict__ W, const float* __restrict__ b,
    float* __restrict__ h, int Nn) {
  int gi = blockIdx.x * 256 + threadIdx.x;
  if (gi >= Nn * 128) return;
  int n = gi >> 7, d = gi & 127;
  float acc = b[d];
#pragma unroll
  for (int j = 0; j < 11; ++j) acc = fmaf(x[(size_t)n * 11 + j], W[j * 128 + d], acc);
#pragma unroll
  for (int j = 0; j < 3; ++j) acc = fmaf(pos[(size_t)n * 3 + j], W[(11 + j) * 128 + d], acc);
  h[gi] = acc;
}

// ---------------- counting sort of edges by dst ----------------
__global__ __launch_bounds__(256) void hist_kernel(const int* __restrict__ dst, int* __restrict__ count, int Ee) {
  int i = blockIdx.x * 256 + threadIdx.x;
  if (i < Ee) atomicAdd(&count[__builtin_nontemporal_load(dst + i)], 1);
}

// 3-kernel parallel exclusive scan over count[n] -> cursor[n]
__global__ __launch_bounds__(1024) void scan1_kernel(
    const int* __restrict__ count, int* __restrict__ cursor, int* __restrict__ bsum, int n) {
  __shared__ int buf[1024];
  int i = blockIdx.x * 1024 + threadIdx.x;
  int v = (i < n) ? count[i] : 0;
  buf[threadIdx.x] = v;
  __syncthreads();
  for (int off = 1; off < 1024; off <<= 1) {
    int t = (threadIdx.x >= off) ? buf[threadIdx.x - off] : 0;
    __syncthreads();
    buf[threadIdx.x] += t;
    __syncthreads();
  }
  if (i < n) cursor[i] = buf[threadIdx.x] - v;  // exclusive within block
  if (threadIdx.x == 1023) bsum[blockIdx.x] = buf[1023];
}
__global__ __launch_bounds__(1024) void scan2_kernel(int* __restrict__ bsum, int nb) {
  __shared__ int buf[1024];
  int v = (threadIdx.x < nb) ? bsum[threadIdx.x] : 0;
  buf[threadIdx.x] = v;
  __syncthreads();
  for (int off = 1; off < 1024; off <<= 1) {
    int t = (threadIdx.x >= off) ? buf[threadIdx.x - off] : 0;
    __syncthreads();
    buf[threadIdx.x] += t;
    __syncthreads();
  }
  if (threadIdx.x < nb) bsum[threadIdx.x] = buf[threadIdx.x] - v;  // exclusive
}
__global__ __launch_bounds__(1024) void scan3_kernel(
    int* __restrict__ cursor, const int* __restrict__ bsum, int n) {
  int i = blockIdx.x * 1024 + threadIdx.x;
  if (i < n) cursor[i] += bsum[blockIdx.x];
}

__global__ __launch_bounds__(256) void scatter_kernel(
    const int* __restrict__ src, const int* __restrict__ dst, const float* __restrict__ ea,
    int* __restrict__ cursor, int* __restrict__ dst_s, int* __restrict__ src_s,
    float* __restrict__ ea_s, int Ee) {
  int e = blockIdx.x * 256 + threadIdx.x;
  if (e >= Ee) return;
  int dn = __builtin_nontemporal_load(dst + e);
  int sn = __builtin_nontemporal_load(src + e);
  floatx4 ev = __builtin_nontemporal_load((const floatx4*)(ea + (size_t)e * 4));
  int pos = atomicAdd(&cursor[dn], 1);
  __builtin_nontemporal_store(dn, dst_s + pos);
  __builtin_nontemporal_store(sn, src_s + pos);
  __builtin_nontemporal_store(ev, (floatx4*)(ea_s + (size_t)pos * 4));
}

// per-64-edge-tile segment-start bitmask (bit i = edge 64T+i starts a run)
__global__ __launch_bounds__(256) void mask_kernel(
    const int* __restrict__ dst_s, unsigned long long* __restrict__ masks, int Ee, int nt) {
  int tile = blockIdx.x * 4 + (threadIdx.x >> 6);
  int lane = threadIdx.x & 63;
  if (tile >= nt) return;
  int e = tile * 64 + lane;
  bool start;
  if (e >= Ee || lane == 0) start = true;
  else start = (dst_s[e] != dst_s[e - 1]);
  unsigned long long m = __ballot(start);
  if (lane == 0) masks[tile] = m;
}

// ---------------- pq_kernel: P = h@W1a, Q = h@W1b (bf16 out, MFMA) ----------------
// (standalone for layer 0; later layers fused into upd_kernel)
__global__ __launch_bounds__(256) void pq_kernel(
    const float* __restrict__ h, const unsigned short* __restrict__ W1abT,
    unsigned short* __restrict__ P, unsigned short* __restrict__ Q, int Nn) {
  __shared__ unsigned short hs[64 * TS];
  const int tid = threadIdx.x;
  const int row0 = blockIdx.x * 64;
#pragma unroll
  for (int i = 0; i < 8; ++i) {
    int idx = tid + i * 256;
    int r = idx >> 5, c4 = (idx & 31) << 2;
    float4 v = make_float4(0.f, 0.f, 0.f, 0.f);
    if (row0 + r < Nn) v = *(const float4*)(h + (size_t)(row0 + r) * 128 + c4);
    *(uint2*)&hs[r * TS + c4] = make_uint2(pk2(v.x, v.y), pk2(v.z, v.w));
  }
  __syncthreads();
  const int lane = tid & 63, wv = tid >> 6;
  const int m16 = lane & 15, quad = lane >> 4;
  floatx4 acc[4][4];
#pragma unroll
  for (int mt = 0; mt < 4; ++mt)
#pragma unroll
    for (int nt = 0; nt < 4; ++nt) acc[mt][nt] = (floatx4)(0.0f);
  const __bf16* WT = (const __bf16*)W1abT;
  const __bf16* TlB = (const __bf16*)hs;
#pragma unroll
  for (int kb = 0; kb < 4; ++kb) {
    bf16x8 a[4], w[4];
#pragma unroll
    for (int mt = 0; mt < 4; ++mt)
      a[mt] = *(const bf16x8*)(TlB + (16 * mt + m16) * TS + kb * 32 + quad * 8);
#pragma unroll
    for (int nt = 0; nt < 4; ++nt)
      w[nt] = *(const bf16x8*)(WT + (size_t)(64 * wv + 16 * nt + m16) * 128 + kb * 32 + quad * 8);
#pragma unroll
    for (int mt = 0; mt < 4; ++mt)
#pragma unroll
      for (int nt = 0; nt < 4; ++nt)
        acc[mt][nt] = __builtin_amdgcn_mfma_f32_16x16x32_bf16(w[nt], a[mt], acc[mt][nt], 0, 0, 0);
  }
#pragma unroll
  for (int mt = 0; mt < 4; ++mt) {
    int row = row0 + 16 * mt + m16;
    if (row >= Nn) continue;
#pragma unroll
    for (int nt = 0; nt < 4; ++nt) {
      int n0 = 64 * wv + 16 * nt + 4 * quad;
      floatx4 A = acc[mt][nt];
      uint2 o = make_uint2(pk2(A[0], A[1]), pk2(A[2], A[3]));
      if (n0 < 128) *(uint2*)(P + (size_t)row * 128 + n0) = o;
      else *(uint2*)(Q + (size_t)row * 128 + (n0 - 128)) = o;
    }
  }
}

// ---------------- edge kernel helpers ----------------
static __device__ __forceinline__ void gather_pq(
    const unsigned short* __restrict__ P, const unsigned short* __restrict__ Q,
    const int* __restrict__ sdstBase, const int* __restrict__ ssrcBase,
    int rw, int c0, uint4* pv, uint4* qv) {
#pragma unroll
  for (int p = 0; p < 4; ++p) {
    int slot = 16 * p + rw;
    int dn = sdstBase[slot];
    int dna = dn < 0 ? 0 : dn;
    int sna = ssrcBase[slot];
    pv[p] = *(const uint4*)(P + (size_t)dna * 128 + c0);   // caching load (reused)
    qv[p] = *(const uint4*)(Q + (size_t)sna * 128 + c0);   // caching load (L3-resident)
  }
}

static __device__ __forceinline__ void build_T(
    unsigned short* __restrict__ TlBuf,
    const uint4* pv, const uint4* qv,
    const int* __restrict__ sdstBase, const float* __restrict__ seaBase,
    const float wc[4][8], const float b1r[8], int rw, int c0) {
#pragma unroll
  for (int p = 0; p < 4; ++p) {
    int row = 16 * p + rw;
    int dn = sdstBase[row];
    uint4 out = make_uint4(0u, 0u, 0u, 0u);
    if (dn >= 0) {
      float e0f = seaBase[row * 4 + 0], e1f = seaBase[row * 4 + 1];
      float e2f = seaBase[row * 4 + 2], e3f = seaBase[row * 4 + 3];
      unsigned pu[4] = {pv[p].x, pv[p].y, pv[p].z, pv[p].w};
      unsigned qu[4] = {qv[p].x, qv[p].y, qv[p].z, qv[p].w};
      unsigned ou[4];
#pragma unroll
      for (int g = 0; g < 4; ++g) {
        float plo = ubits(pu[g] << 16), phi = ubits(pu[g] & 0xffff0000u);
        float qlo = ubits(qu[g] << 16), qhi = ubits(qu[g] & 0xffff0000u);
        int j0 = 2 * g, j1 = 2 * g + 1;
        float t0 = plo + qlo + b1r[j0];
        float t1 = phi + qhi + b1r[j1];
        t0 = fmaf(e0f, wc[0][j0], fmaf(e1f, wc[1][j0], fmaf(e2f, wc[2][j0], fmaf(e3f, wc[3][j0], t0))));
        t1 = fmaf(e0f, wc[0][j1], fmaf(e1f, wc[1][j1], fmaf(e2f, wc[2][j1], fmaf(e3f, wc[3][j1], t1))));
        ou[g] = pk2(fmaxf(t0, 0.f), fmaxf(t1, 0.f));
      }
      out = make_uint4(ou[0], ou[1], ou[2], ou[3]);
    }
    *(uint4*)&TlBuf[row * TS + c0] = out;
  }
}

static __device__ __forceinline__ void mfma_B(
    const unsigned short* __restrict__ TlBuf, const __bf16* __restrict__ WT,
    int m16, int quad, int wv, floatx4 acc[4][2]) {
#pragma unroll
  for (int mt = 0; mt < 4; ++mt) { acc[mt][0] = (floatx4)(0.0f); acc[mt][1] = (floatx4)(0.0f); }
  const __bf16* TlB = (const __bf16*)TlBuf;
#pragma unroll
  for (int kb = 0; kb < 4; ++kb) {
    bf16x8 w0 = *(const bf16x8*)(WT + (size_t)(32 * wv + m16) * 128 + kb * 32 + quad * 8);
    bf16x8 w1 = *(const bf16x8*)(WT + (size_t)(32 * wv + 16 + m16) * 128 + kb * 32 + quad * 8);
    bf16x8 a[4];
#pragma unroll
    for (int mt = 0; mt < 4; ++mt)
      a[mt] = *(const bf16x8*)(TlB + (16 * mt + m16) * TS + kb * 32 + quad * 8);
#pragma unroll
    for (int mt = 0; mt < 4; ++mt) {
      acc[mt][0] = __builtin_amdgcn_mfma_f32_16x16x32_bf16(w0, a[mt], acc[mt][0], 0, 0, 0);
      acc[mt][1] = __builtin_amdgcn_mfma_f32_16x16x32_bf16(w1, a[mt], acc[mt][1], 0, 0, 0);
    }
  }
}

static __device__ __forceinline__ void epi_m(
    unsigned short* __restrict__ TlBuf, floatx4 acc[4][2],
    const float* __restrict__ B2f, int m16, int quad, int wv) {
  int n0 = 32 * wv + 4 * quad;
  float4 bv0 = *(const float4*)(B2f + n0);
  float4 bv1 = *(const float4*)(B2f + n0 + 16);
#pragma unroll
  for (int mt = 0; mt < 4; ++mt) {
    int row = 16 * mt + m16;
    floatx4 A0 = acc[mt][0], A1 = acc[mt][1];
    *(uint2*)&TlBuf[row * TS + n0] =
        make_uint2(pk2(fmaxf(A0[0] + bv0.x, 0.f), fmaxf(A0[1] + bv0.y, 0.f)),
                   pk2(fmaxf(A0[2] + bv0.z, 0.f), fmaxf(A0[3] + bv0.w, 0.f)));
    *(uint2*)&TlBuf[row * TS + n0 + 16] =
        make_uint2(pk2(fmaxf(A1[0] + bv1.x, 0.f), fmaxf(A1[1] + bv1.y, 0.f)),
                   pk2(fmaxf(A1[2] + bv1.z, 0.f), fmaxf(A1[3] + bv1.w, 0.f)));
  }
}

// mask-driven segmented reduce; thread covers cols c4..c4+3 and 64+c4..64+c4+3
// -> each store across the 16 participating consecutive lanes is 256 B contiguous.
static __device__ __forceinline__ void seg_reduce(
    const unsigned short* __restrict__ TlBuf, const int* __restrict__ sdstBase,
    unsigned long long mask, float* __restrict__ aggr, int tid) {
  const int c4 = (tid & 15) << 2;
  const int st = tid >> 4;
  const int dfirst = sdstBase[0], dlast = sdstBase[63];
  for (int s = st; s < 64; s += 16) {
    if (!(mask & (1ull << s))) continue;
    int dn = sdstBase[s];
    if (dn < 0) continue;
    int end;
    if (s >= 63) end = 64;
    else {
      unsigned long long m2 = mask >> (s + 1);
      end = m2 ? (s + 1 + (int)__builtin_ctzll(m2)) : 64;
    }
    float a0 = 0.f, a1 = 0.f, a2 = 0.f, a3 = 0.f, a4 = 0.f, a5 = 0.f, a6 = 0.f, a7 = 0.f;
    for (int e = s; e < end; ++e) {
      uint2 v1 = *(const uint2*)&TlBuf[e * TS + c4];
      uint2 v2 = *(const uint2*)&TlBuf[e * TS + 64 + c4];
      a0 += ubits(v1.x << 16); a1 += ubits(v1.x & 0xffff0000u);
      a2 += ubits(v1.y << 16); a3 += ubits(v1.y & 0xffff0000u);
      a4 += ubits(v2.x << 16); a5 += ubits(v2.x & 0xffff0000u);
      a6 += ubits(v2.y << 16); a7 += ubits(v2.y & 0xffff0000u);
    }
    float* ap = aggr + (size_t)dn * 128 + c4;
    if (dn == dfirst || dn == dlast) {
      atomicAdd(ap + 0, a0); atomicAdd(ap + 1, a1);
      atomicAdd(ap + 2, a2); atomicAdd(ap + 3, a3);
      atomicAdd(ap + 64, a4); atomicAdd(ap + 65, a5);
      atomicAdd(ap + 66, a6); atomicAdd(ap + 67, a7);
    } else {
      floatx4 w1; w1[0] = a0; w1[1] = a1; w1[2] = a2; w1[3] = a3;
      floatx4 w2; w2[0] = a4; w2[1] = a5; w2[2] = a6; w2[3] = a7;
      __builtin_nontemporal_store(w1, (floatx4*)ap);
      __builtin_nontemporal_store(w2, (floatx4*)(ap + 64));
    }
  }
}

// ---------------- edge message kernel: 2 tiles/block, pipelined ----------------
__global__ __launch_bounds__(256, 4) void edge_kernel(
    const unsigned short* __restrict__ P, const unsigned short* __restrict__ Q,
    const float* __restrict__ ea_s, const int* __restrict__ dst_s, const int* __restrict__ src_s,
    const unsigned long long* __restrict__ masks,
    const float* __restrict__ W1c, const float* __restrict__ b1,
    const unsigned short* __restrict__ W2fT, const float* __restrict__ B2f,
    float* __restrict__ aggr, int Ee, int nT) {
  __shared__ unsigned short Tl[2][64 * TS];
  __shared__ float sea[128 * 4];
  __shared__ int sdst[128], ssrc[128];
  const int tid = threadIdx.x;
  const int t0 = blockIdx.x * 2, t1 = t0 + 1;
  const int e0 = t0 * 64;
  const bool has1 = (t1 < nT);
  const unsigned long long mask0 = masks[t0];
  const unsigned long long mask1 = has1 ? masks[t1] : 0ull;
  if (tid < 128) {
    int e = e0 + tid;
    bool ok = e < Ee;
    sdst[tid] = ok ? __builtin_nontemporal_load(dst_s + e) : -1;
    ssrc[tid] = ok ? __builtin_nontemporal_load(src_s + e) : 0;
    floatx4 ev = (floatx4)(0.0f);
    if (ok) ev = __builtin_nontemporal_load((const floatx4*)(ea_s + (size_t)e * 4));
    *(floatx4*)&sea[tid * 4] = ev;
  }
  // per-thread W1c slice: cols c0..c0+7
  const int rw = tid >> 4, c0 = (tid & 15) << 3;
  float wc[4][8], b1r[8];
#pragma unroll
  for (int r = 0; r < 4; ++r) {
    *(float4*)&wc[r][0] = *(const float4*)(W1c + r * 128 + c0);
    *(float4*)&wc[r][4] = *(const float4*)(W1c + r * 128 + c0 + 4);
  }
  *(float4*)&b1r[0] = *(const float4*)(b1 + c0);
  *(float4*)&b1r[4] = *(const float4*)(b1 + c0 + 4);
  __syncthreads();

  const int lane = tid & 63, wv = tid >> 6;
  const int m16 = lane & 15, quad = lane >> 4;
  const __bf16* WT = (const __bf16*)W2fT;

  // --- pipeline ---
  uint4 pv[4], qv[4], pv1[4], qv1[4];
  gather_pq(P, Q, sdst, ssrc, rw, c0, pv, qv);                 // tile0 gathers
  build_T(Tl[0], pv, qv, sdst, sea, wc, b1r, rw, c0);          // T0 -> Tl[0]
  if (has1) gather_pq(P, Q, sdst + 64, ssrc + 64, rw, c0, pv1, qv1);  // tile1 gathers in flight
  __syncthreads();                                             // Tl[0] ready

  floatx4 acc[4][2];
  mfma_B(Tl[0], WT, m16, quad, wv, acc);                       // B0 (reads Tl[0])
  if (has1) build_T(Tl[1], pv1, qv1, sdst + 64, sea + 256, wc, b1r, rw, c0);  // T1 -> Tl[1]
  __syncthreads();                                             // B0 reads done; Tl[1] ready

  epi_m(Tl[0], acc, B2f, m16, quad, wv);                       // m0 -> Tl[0]
  floatx4 acc1[4][2];
  if (has1) mfma_B(Tl[1], WT, m16, quad, wv, acc1);            // B1 (reads Tl[1])
  __syncthreads();                                             // m0 ready; B1 reads done

  seg_reduce(Tl[0], sdst, mask0, aggr, tid);                   // C0
  if (has1) {
    epi_m(Tl[1], acc1, B2f, m16, quad, wv);                    // m1 -> Tl[1]
    __syncthreads();                                           // m1 ready
    seg_reduce(Tl[1], sdst + 64, mask1, aggr, tid);            // C1
  }
}

// ---------------- fused update MLP (+ next-layer P/Q), MFMA, in-place h ----------------
__global__ __launch_bounds__(256) void upd_kernel(
    float* __restrict__ h, const float* __restrict__ aggr,
    const unsigned short* __restrict__ U1T, const float* __restrict__ ub1,
    const unsigned short* __restrict__ uW2fT, const float* __restrict__ uB2f, int Nn,
    const unsigned short* __restrict__ W1abT_next,
    unsigned short* __restrict__ P, unsigned short* __restrict__ Q) {
  __shared__ unsigned short as_[64 * AS];  // [h|aggr]; u1 overlay; then h_new overlay
  const int tid = threadIdx.x;
  const int row0 = blockIdx.x * 64;
#pragma unroll
  for (int i = 0; i < 8; ++i) {
    int idx = tid + i * 256;
    int r = idx >> 5, c4 = (idx & 31) << 2;
    float4 v = make_float4(0.f, 0.f, 0.f, 0.f);
    if (row0 + r < Nn) v = *(const float4*)(h + (size_t)(row0 + r) * 128 + c4);
    *(uint2*)&as_[r * AS + c4] = make_uint2(pk2(v.x, v.y), pk2(v.z, v.w));
  }
#pragma unroll
  for (int i = 0; i < 8; ++i) {
    int idx = tid + i * 256;
    int r = idx >> 5, c4 = (idx & 31) << 2;
    floatx4 v = (floatx4)(0.0f);
    if (row0 + r < Nn) v = __builtin_nontemporal_load((const floatx4*)(aggr + (size_t)(row0 + r) * 128 + c4));
    *(uint2*)&as_[r * AS + 128 + c4] = make_uint2(pk2(v[0], v[1]), pk2(v[2], v[3]));
  }
  __syncthreads();
  const int lane = tid & 63, wv = tid >> 6;
  const int m16 = lane & 15, quad = lane >> 4;
  const __bf16* asB = (const __bf16*)as_;
  unsigned short* u1s = as_;  // overlay (TS stride)
  // pass 1: u1 = relu([h|aggr]@U1 + ub1), K=256
  {
    floatx4 acc[4][2];
#pragma unroll
    for (int mt = 0; mt < 4; ++mt) { acc[mt][0] = (floatx4)(0.0f); acc[mt][1] = (floatx4)(0.0f); }
    const __bf16* WT = (const __bf16*)U1T;
#pragma unroll
    for (int kb = 0; kb < 8; ++kb) {
      bf16x8 w0 = *(const bf16x8*)(WT + (size_t)(32 * wv + m16) * 256 + kb * 32 + quad * 8);
      bf16x8 w1 = *(const bf16x8*)(WT + (size_t)(32 * wv + 16 + m16) * 256 + kb * 32 + quad * 8);
      bf16x8 a[4];
#pragma unroll
      for (int mt = 0; mt < 4; ++mt)
        a[mt] = *(const bf16x8*)(asB + (16 * mt + m16) * AS + kb * 32 + quad * 8);
#pragma unroll
      for (int mt = 0; mt < 4; ++mt) {
        acc[mt][0] = __builtin_amdgcn_mfma_f32_16x16x32_bf16(w0, a[mt], acc[mt][0], 0, 0, 0);
        acc[mt][1] = __builtin_amdgcn_mfma_f32_16x16x32_bf16(w1, a[mt], acc[mt][1], 0, 0, 0);
      }
    }
    __syncthreads();  // pass-1 reads of as_ complete -> safe to overlay u1
    int n0 = 32 * wv + 4 * quad;
    float4 bv0 = *(const float4*)(ub1 + n0);
    float4 bv1 = *(const float4*)(ub1 + n0 + 16);
#pragma unroll
    for (int mt = 0; mt < 4; ++mt) {
      int row = 16 * mt + m16;
      floatx4 A0 = acc[mt][0], A1 = acc[mt][1];
      *(uint2*)&u1s[row * TS + n0] =
          make_uint2(pk2(fmaxf(A0[0] + bv0.x, 0.f), fmaxf(A0[1] + bv0.y, 0.f)),
                     pk2(fmaxf(A0[2] + bv0.z, 0.f), fmaxf(A0[3] + bv0.w, 0.f)));
      *(uint2*)&u1s[row * TS + n0 + 16] =
          make_uint2(pk2(fmaxf(A1[0] + bv1.x, 0.f), fmaxf(A1[1] + bv1.y, 0.f)),
                     pk2(fmaxf(A1[2] + bv1.z, 0.f), fmaxf(A1[3] + bv1.w, 0.f)));
    }
  }
  __syncthreads();
  // pass 2: h_new = h + relu(u1@U2f + uB2f), K=128; write global + LDS bf16
  {
    floatx4 acc[4][2];
#pragma unroll
    for (int mt = 0; mt < 4; ++mt) { acc[mt][0] = (floatx4)(0.0f); acc[mt][1] = (floatx4)(0.0f); }
    const __bf16* WT = (const __bf16*)uW2fT;
    const __bf16* u1B = (const __bf16*)u1s;
#pragma unroll
    for (int kb = 0; kb < 4; ++kb) {
      bf16x8 w0 = *(const bf16x8*)(WT + (size_t)(32 * wv + m16) * 128 + kb * 32 + quad * 8);
      bf16x8 w1 = *(const bf16x8*)(WT + (size_t)(32 * wv + 16 + m16) * 128 + kb * 32 + quad * 8);
      bf16x8 a[4];
#pragma unroll
      for (int mt = 0; mt < 4; ++mt)
        a[mt] = *(const bf16x8*)(u1B + (16 * mt + m16) * TS + kb * 32 + quad * 8);
#pragma unroll
      for (int mt = 0; mt < 4; ++mt) {
        acc[mt][0] = __builtin_amdgcn_mfma_f32_16x16x32_bf16(w0, a[mt], acc[mt][0], 0, 0, 0);
        acc[mt][1] = __builtin_amdgcn_mfma_f32_16x16x32_bf16(w1, a[mt], acc[mt][1], 0, 0, 0);
      }
    }
    __syncthreads();  // pass-2 reads of u1s complete -> safe to overlay h_new
    int n0 = 32 * wv + 4 * quad;
    float4 bv0 = *(const float4*)(uB2f + n0);
    float4 bv1 = *(const float4*)(uB2f + n0 + 16);
#pragma unroll
    for (int mt = 0; mt < 4; ++mt) {
      int rloc = 16 * mt + m16;
      int row = row0 + rloc;
      floatx4 A0 = acc[mt][0], A1 = acc[mt][1];
      if (row < Nn) {
        float* hp0 = h + (size_t)row * 128 + n0;
        float4 hv0 = *(float4*)hp0;
        float4 o0 = make_float4(hv0.x + fmaxf(A0[0] + bv0.x, 0.f), hv0.y + fmaxf(A0[1] + bv0.y, 0.f),
                                hv0.z + fmaxf(A0[2] + bv0.z, 0.f), hv0.w + fmaxf(A0[3] + bv0.w, 0.f));
        *(float4*)hp0 = o0;
        float* hp1 = hp0 + 16;
        float4 hv1 = *(float4*)hp1;
        float4 o1 = make_float4(hv1.x + fmaxf(A1[0] + bv1.x, 0.f), hv1.y + fmaxf(A1[1] + bv1.y, 0.f),
                                hv1.z + fmaxf(A1[2] + bv1.z, 0.f), hv1.w + fmaxf(A1[3] + bv1.w, 0.f));
        *(float4*)hp1 = o1;
        if (W1abT_next) {
          *(uint2*)&u1s[rloc * TS + n0] = make_uint2(pk2(o0.x, o0.y), pk2(o0.z, o0.w));
          *(uint2*)&u1s[rloc * TS + n0 + 16] = make_uint2(pk2(o1.x, o1.y), pk2(o1.z, o1.w));
        }
      } else if (W1abT_next) {
        *(uint2*)&u1s[rloc * TS + n0] = make_uint2(0u, 0u);
        *(uint2*)&u1s[rloc * TS + n0 + 16] = make_uint2(0u, 0u);
      }
    }
  }
  // fused next-layer P/Q from h_new tile in LDS
  if (W1abT_next) {
    __syncthreads();
    floatx4 pacc[4][4];
#pragma unroll
    for (int mt = 0; mt < 4; ++mt)
#pragma unroll
      for (int nt = 0; nt < 4; ++nt) pacc[mt][nt] = (floatx4)(0.0f);
    const __bf16* WT = (const __bf16*)W1abT_next;
    const __bf16* hB = (const __bf16*)u1s;
#pragma unroll
    for (int kb = 0; kb < 4; ++kb) {
      bf16x8 a[4], w[4];
#pragma unroll
      for (int mt = 0; mt < 4; ++mt)
        a[mt] = *(const bf16x8*)(hB + (16 * mt + m16) * TS + kb * 32 + quad * 8);
#pragma unroll
      for (int nt = 0; nt < 4; ++nt)
        w[nt] = *(const bf16x8*)(WT + (size_t)(64 * wv + 16 * nt + m16) * 128 + kb * 32 + quad * 8);
#pragma unroll
      for (int mt = 0; mt < 4; ++mt)
#pragma unroll
        for (int nt = 0; nt < 4; ++nt)
          pacc[mt][nt] = __builtin_amdgcn_mfma_f32_16x16x32_bf16(w[nt], a[mt], pacc[mt][nt], 0, 0, 0);
    }
#pragma unroll
    for (int mt = 0; mt < 4; ++mt) {
      int row = row0 + 16 * mt + m16;
      if (row >= Nn) continue;
#pragma unroll
      for (int nt = 0; nt < 4; ++nt) {
        int n0 = 64 * wv + 16 * nt + 4 * quad;
        floatx4 A = pacc[mt][nt];
        uint2 o = make_uint2(pk2(A[0], A[1]), pk2(A[2], A[3]));
        if (n0 < 128) *(uint2*)(P + (size_t)row * 128 + n0) = o;
        else *(uint2*)(Q + (size_t)row * 128 + (n0 - 128)) = o;
      }
    }
  }
}

// ---------------- pooling ----------------
__global__ __launch_bounds__(128) void pool_sum_kernel(
    const float* __restrict__ h, const int* __restrict__ batch,
    float* __restrict__ sums, int* __restrict__ gcnt, int Nn) {
  int n0 = blockIdx.x * 256;
  if (n0 >= Nn) return;
  int nend = min(n0 + 256, Nn);
  int d = threadIdx.x;
  int gcur = batch[n0];
  float run = 0.f;
  int cnt = 0;
  for (int n = n0; n < nend; ++n) {
    int g = batch[n];
    if (g != gcur) {
      atomicAdd(&sums[(size_t)gcur * 128 + d], run);
      if (d == 0) atomicAdd(&gcnt[gcur], cnt);
      run = 0.f; cnt = 0; gcur = g;
    }
    run += h[(size_t)n * 128 + d];
    cnt += 1;
  }
  atomicAdd(&sums[(size_t)gcur * 128 + d], run);
  if (d == 0) atomicAdd(&gcnt[gcur], cnt);
}

__global__ __launch_bounds__(128) void pred_kernel(
    const float* __restrict__ sums, const int* __restrict__ gcnt,
    const float* __restrict__ pw, const float* __restrict__ pb, float* __restrict__ out) {
  __shared__ float red[2];
  int g = blockIdx.x, d = threadIdx.x;
  float c = fmaxf((float)gcnt[g], 1.f);
  float v = (sums[(size_t)g * 128 + d] / c) * pw[d];
  for (int o = 32; o > 0; o >>= 1) v += __shfl_down(v, o, 64);
  if ((d & 63) == 0) red[d >> 6] = v;
  __syncthreads();
  if (d == 0) out[g] = red[0] + red[1] + pb[0];
}

// ---------------- launch ----------------
extern "C" void kernel_launch(void* const* d_in, const int* in_sizes, int n_in,
                              void* d_out, int out_size, void* d_ws, size_t ws_size,
                              hipStream_t stream) {
  const float* x = (const float*)d_in[0];
  const float* pos = (const float*)d_in[1];
  const int* ei = (const int*)d_in[2];
  const float* ea = (const float*)d_in[3];
  const int* batch = (const int*)d_in[4];
  const float* lin_w = (const float*)d_in[5];
  const float* lin_b = (const float*)d_in[6];
  const float* mw1 = (const float*)d_in[7];
  const float* mb1 = (const float*)d_in[8];
  const float* mg = (const float*)d_in[9];
  const float* mbb = (const float*)d_in[10];
  const float* mm = (const float*)d_in[11];
  const float* mv = (const float*)d_in[12];
  const float* mw2 = (const float*)d_in[13];
  const float* mb2 = (const float*)d_in[14];
  const float* uw1 = (const float*)d_in[15];
  const float* ub1 = (const float*)d_in[16];
  const float* ug = (const float*)d_in[17];
  const float* ubb = (const float*)d_in[18];
  const float* um = (const float*)d_in[19];
  const float* uv = (const float*)d_in[20];
  const float* uw2 = (const float*)d_in[21];
  const float* ub2 = (const float*)d_in[22];
  const float* pw = (const float*)d_in[23];
  const float* pb = (const float*)d_in[24];
  float* out = (float*)d_out;

  const int Nn = in_sizes[0] / 11;
  const int Ee = in_sizes[3] / 4;
  const int* srcp = ei;        // edge_index[0] = source j
  const int* dstp = ei + Ee;   // edge_index[1] = target i

  char* wsb = (char*)d_ws;
  size_t off = 0;
  auto alloc = [&](size_t bytes) -> void* {
    void* p = wsb + off;
    off = (off + bytes + 255) & ~(size_t)255;
    return p;
  };
  float* h = (float*)alloc((size_t)Nn * 128 * 4);
  unsigned short* Pb = (unsigned short*)alloc((size_t)Nn * 128 * 2);
  unsigned short* Qb = (unsigned short*)alloc((size_t)Nn * 128 * 2);
  float* aggr = (float*)alloc((size_t)Nn * 128 * 4);
  int* dst_s = (int*)alloc((size_t)Ee * 4);
  int* src_s = (int*)alloc((size_t)Ee * 4);
  float* ea_s = (float*)alloc((size_t)Ee * 16);
  int* count = (int*)alloc((size_t)Nn * 4);
  int* cursor = (int*)alloc((size_t)Nn * 4);
  int* bsum = (int*)alloc((size_t)1024 * 4);
  const int nTiles = (Ee + 63) / 64;
  unsigned long long* masks = (unsigned long long*)alloc((size_t)nTiles * 8);
  unsigned short* mW2fT = (unsigned short*)alloc((size_t)4 * 128 * 128 * 2);
  unsigned short* uW2fT = (unsigned short*)alloc((size_t)4 * 128 * 128 * 2);
  unsigned short* W1abT = (unsigned short*)alloc((size_t)4 * 256 * 128 * 2);
  unsigned short* U1T = (unsigned short*)alloc((size_t)4 * 128 * 256 * 2);
  float* mB2f = (float*)alloc((size_t)4 * 128 * 4);
  float* uB2f = (float*)alloc((size_t)4 * 128 * 4);
  float* sums = (float*)alloc((size_t)out_size * 128 * 4);
  int* gcnt = (int*)alloc((size_t)out_size * 4);
  (void)ws_size; (void)n_in;

  fold_kernel<<<8, 128, 0, stream>>>(mw2, mb2, mg, mbb, mm, mv,
                                     uw2, ub2, ug, ubb, um, uv,
                                     mW2fT, mB2f, uW2fT, uB2f);
  transp_kernel<<<8, 256, 0, stream>>>(mw1, uw1, W1abT, U1T);
  lin_in_kernel<<<(Nn * 128 + 255) / 256, 256, 0, stream>>>(x, pos, lin_w, lin_b, h, Nn);

  hipMemsetAsync(count, 0, (size_t)Nn * 4, stream);
  hist_kernel<<<(Ee + 255) / 256, 256, 0, stream>>>(dstp, count, Ee);
  const int NB = (Nn + 1023) / 1024;
  scan1_kernel<<<NB, 1024, 0, stream>>>(count, cursor, bsum, Nn);
  scan2_kernel<<<1, 1024, 0, stream>>>(bsum, NB);
  scan3_kernel<<<NB, 1024, 0, stream>>>(cursor, bsum, Nn);
  scatter_kernel<<<(Ee + 255) / 256, 256, 0, stream>>>(srcp, dstp, ea, cursor,
                                                       dst_s, src_s, ea_s, Ee);
  mask_kernel<<<(nTiles + 3) / 4, 256, 0, stream>>>(dst_s, masks, Ee, nTiles);

  const int gN = (Nn + 63) / 64;
  pq_kernel<<<gN, 256, 0, stream>>>(h, W1abT, Pb, Qb, Nn);  // layer 0 P/Q
  for (int l = 0; l < 4; ++l) {
    hipMemsetAsync(aggr, 0, (size_t)Nn * 128 * 4, stream);
    edge_kernel<<<(nTiles + 1) / 2, 256, 0, stream>>>(
        Pb, Qb, ea_s, dst_s, src_s, masks,
        mw1 + (size_t)l * 260 * 128 + 256 * 128, mb1 + l * 128,
        mW2fT + (size_t)l * 16384, mB2f + l * 128, aggr, Ee, nTiles);
    upd_kernel<<<gN, 256, 0, stream>>>(
        h, aggr, U1T + (size_t)l * 128 * 256, ub1 + l * 128,
        uW2fT + (size_t)l * 16384, uB2f + l * 128, Nn,
        (l < 3) ? (W1abT + (size_t)(l + 1) * 256 * 128) : nullptr, Pb, Qb);
  }

  hipMemsetAsync(sums, 0, (size_t)out_size * 128 * 4, stream);
  hipMemsetAsync(gcnt, 0, (size_t)out_size * 4, stream);
  pool_sum_kernel<<<(Nn + 255) / 256, 128, 0, stream>>>(h, batch, sums, gcnt, Nn);
  pred_kernel<<<out_size, 128, 0, stream>>>(sums, gcnt, pw, pb, out);
}

// Round 9
// 1937.763 us; speedup vs baseline: 1.0398x; 1.0398x over previous
//
#include <hip/hip_runtime.h>
#include <hip/hip_bf16.h>

// MPNN: N=100000 nodes, E=1600000 edges, D=128, L=4, G=64.
// All GEMM-shaped work on MFMA bf16 (fp32 accumulate), fp32 residual stream h.
//   prep: fold BN into W2 (both MLPs), transpose all B-matrices to [n][k] bf16,
//         counting-sort edges by dst, per-64-edge-tile segment-start bitmasks.
//   per layer:
//     edge_kernel (2 tiles/block, double-buffered pipeline, XCD-swizzled):
//         t = relu(P[dst]+Q[src]+ea@W1c+b1) -> bf16 LDS (Tl[buf])
//         m = relu(t@W2f+b2f)   (MFMA) -> written back into Tl[buf]
//         mask-driven segmented reduce -> aggr (256-B-contiguous stores)
//     upd_kernel:  u1 = relu([h|aggr]@U1+ub1) (MFMA K=256) -> bf16 LDS overlay
//                  h += relu(u1@U2f+uB2f)     (MFMA K=128), in-place
//                  + fused next-layer P/Q = h_new @ W1ab (via LDS h_new tile)
// XCD swizzle: default dispatch round-robins blocks over 8 XCDs; remap
// b -> (b&7)*per + (b>>3) so each XCD owns a contiguous edge range -> its
// P-gather slice (~3.2MB) fits the 4MB per-XCD L2; aggr writes XCD-local.
// (R8 lesson: __builtin_nontemporal_* bypasses L2 on gfx950 -> reverted;
//  launch_bounds(256,4) spilled the pipeline arrays -> back to (256,3).)

#define EPSBN 1e-5f
#define TS 136   // bf16 elems per LDS row for 128-wide tiles (272 B = 17*16 B)
#define AS 264   // bf16 elems per LDS row for 256-wide tiles (528 B = 33*16 B)

typedef __bf16 bf16x8 __attribute__((ext_vector_type(8)));
typedef float floatx4 __attribute__((ext_vector_type(4)));

static __device__ __forceinline__ unsigned short f2b(float f) {
  union { float f; unsigned u; } v; v.f = f;
  unsigned u = v.u;
  return (unsigned short)((u + 0x7fffu + ((u >> 16) & 1u)) >> 16);  // RNE
}
static __device__ __forceinline__ unsigned pk2(float lo, float hi) {
  union { __hip_bfloat162 h; unsigned u; } v;
  v.h = __float22bfloat162_rn(make_float2(lo, hi));  // v_cvt_pk_bf16_f32
  return v.u;
}
static __device__ __forceinline__ float ubits(unsigned u) {
  union { unsigned u; float f; } v; v.u = u; return v.f;
}

// ---------------- fold BN into second linear, write transposed bf16 ----------------
__global__ __launch_bounds__(128) void fold_kernel(
    const float* __restrict__ mw2, const float* __restrict__ mb2,
    const float* __restrict__ mg, const float* __restrict__ mb,
    const float* __restrict__ mm, const float* __restrict__ mv,
    const float* __restrict__ uw2, const float* __restrict__ ub2,
    const float* __restrict__ ug, const float* __restrict__ ub,
    const float* __restrict__ um, const float* __restrict__ uv,
    unsigned short* __restrict__ mW2fT, float* __restrict__ mB2f,
    unsigned short* __restrict__ uW2fT, float* __restrict__ uB2f) {
  int l = blockIdx.x & 3;
  bool isu = blockIdx.x >= 4;
  const float* W2 = (isu ? uw2 : mw2) + (size_t)l * 128 * 128;
  const float* b2 = (isu ? ub2 : mb2) + l * 128;
  const float* gg = (isu ? ug : mg) + l * 128;
  const float* bb = (isu ? ub : mb) + l * 128;
  const float* mn = (isu ? um : mm) + l * 128;
  const float* vr = (isu ? uv : mv) + l * 128;
  unsigned short* WfT = (isu ? uW2fT : mW2fT) + (size_t)l * 128 * 128;
  float* Bf = (isu ? uB2f : mB2f) + l * 128;
  __shared__ float a[128], c[128];
  int d = threadIdx.x;
  float ad = gg[d] * rsqrtf(vr[d] + EPSBN);
  a[d] = ad;
  c[d] = bb[d] - mn[d] * ad;
  __syncthreads();
  float acc = b2[d];
  for (int k = 0; k < 128; ++k) {
    float w = W2[k * 128 + d];
    WfT[(size_t)d * 128 + k] = f2b(a[k] * w);  // [n][k] bf16
    acc = fmaf(c[k], w, acc);
  }
  Bf[d] = acc;
}

// ---------------- transpose W1ab / U1 to [n][k] bf16 ----------------
__global__ __launch_bounds__(256) void transp_kernel(
    const float* __restrict__ mw1, const float* __restrict__ uw1,
    unsigned short* __restrict__ W1abT, unsigned short* __restrict__ U1T) {
  int l = blockIdx.x & 3;
  bool isu = blockIdx.x >= 4;
  int tid = threadIdx.x;
  if (!isu) {
    const float* W = mw1 + (size_t)l * 260 * 128;
    unsigned short* T = W1abT + (size_t)l * 256 * 128;
    for (int i = tid; i < 256 * 128; i += 256) {
      int n = i >> 7, k = i & 127;
      float v = (n < 128) ? W[(size_t)k * 128 + n] : W[(size_t)(128 + k) * 128 + (n - 128)];
      T[i] = f2b(v);
    }
  } else {
    const float* W = uw1 + (size_t)l * 256 * 128;
    unsigned short* T = U1T + (size_t)l * 128 * 256;
    for (int i = tid; i < 128 * 256; i += 256) {
      int n = i >> 8, k = i & 255;
      T[i] = f2b(W[(size_t)k * 128 + n]);
    }
  }
}

// ---------------- input projection ----------------
__global__ __launch_bounds__(256) void lin_in_kernel(
    const float* __restrict__ x, const float* __restrict__ pos,
    const float* __restrict__ W, const float* __restrict__ b,
    float* __restrict__ h, int Nn) {
  int gi = blockIdx.x * 256 + threadIdx.x;
  if (gi >= Nn * 128) return;
  int n = gi >> 7, d = gi & 127;
  float acc = b[d];
#pragma unroll
  for (int j = 0; j < 11; ++j) acc = fmaf(x[(size_t)n * 11 + j], W[j * 128 + d], acc);
#pragma unroll
  for (int j = 0; j < 3; ++j) acc = fmaf(pos[(size_t)n * 3 + j], W[(11 + j) * 128 + d], acc);
  h[gi] = acc;
}

// ---------------- counting sort of edges by dst ----------------
__global__ __launch_bounds__(256) void hist_kernel(const int* __restrict__ dst, int* __restrict__ count, int Ee) {
  int i = blockIdx.x * 256 + threadIdx.x;
  if (i < Ee) atomicAdd(&count[dst[i]], 1);
}

// 3-kernel parallel exclusive scan over count[n] -> cursor[n]
__global__ __launch_bounds__(1024) void scan1_kernel(
    const int* __restrict__ count, int* __restrict__ cursor, int* __restrict__ bsum, int n) {
  __shared__ int buf[1024];
  int i = blockIdx.x * 1024 + threadIdx.x;
  int v = (i < n) ? count[i] : 0;
  buf[threadIdx.x] = v;
  __syncthreads();
  for (int off = 1; off < 1024; off <<= 1) {
    int t = (threadIdx.x >= off) ? buf[threadIdx.x - off] : 0;
    __syncthreads();
    buf[threadIdx.x] += t;
    __syncthreads();
  }
  if (i < n) cursor[i] = buf[threadIdx.x] - v;  // exclusive within block
  if (threadIdx.x == 1023) bsum[blockIdx.x] = buf[1023];
}
__global__ __launch_bounds__(1024) void scan2_kernel(int* __restrict__ bsum, int nb) {
  __shared__ int buf[1024];
  int v = (threadIdx.x < nb) ? bsum[threadIdx.x] : 0;
  buf[threadIdx.x] = v;
  __syncthreads();
  for (int off = 1; off < 1024; off <<= 1) {
    int t = (threadIdx.x >= off) ? buf[threadIdx.x - off] : 0;
    __syncthreads();
    buf[threadIdx.x] += t;
    __syncthreads();
  }
  if (threadIdx.x < nb) bsum[threadIdx.x] = buf[threadIdx.x] - v;  // exclusive
}
__global__ __launch_bounds__(1024) void scan3_kernel(
    int* __restrict__ cursor, const int* __restrict__ bsum, int n) {
  int i = blockIdx.x * 1024 + threadIdx.x;
  if (i < n) cursor[i] += bsum[blockIdx.x];
}

__global__ __launch_bounds__(256) void scatter_kernel(
    const int* __restrict__ src, const int* __restrict__ dst, const float* __restrict__ ea,
    int* __restrict__ cursor, int* __restrict__ dst_s, int* __restrict__ src_s,
    float* __restrict__ ea_s, int Ee) {
  int e = blockIdx.x * 256 + threadIdx.x;
  if (e >= Ee) return;
  int dn = dst[e];
  int pos = atomicAdd(&cursor[dn], 1);
  dst_s[pos] = dn;
  src_s[pos] = src[e];
  *(float4*)(ea_s + (size_t)pos * 4) = *(const float4*)(ea + (size_t)e * 4);
}

// per-64-edge-tile segment-start bitmask (bit i = edge 64T+i starts a run)
__global__ __launch_bounds__(256) void mask_kernel(
    const int* __restrict__ dst_s, unsigned long long* __restrict__ masks, int Ee, int nt) {
  int tile = blockIdx.x * 4 + (threadIdx.x >> 6);
  int lane = threadIdx.x & 63;
  if (tile >= nt) return;
  int e = tile * 64 + lane;
  bool start;
  if (e >= Ee || lane == 0) start = true;
  else start = (dst_s[e] != dst_s[e - 1]);
  unsigned long long m = __ballot(start);
  if (lane == 0) masks[tile] = m;
}

// ---------------- pq_kernel: P = h@W1a, Q = h@W1b (bf16 out, MFMA) ----------------
// (standalone for layer 0; later layers fused into upd_kernel)
__global__ __launch_bounds__(256) void pq_kernel(
    const float* __restrict__ h, const unsigned short* __restrict__ W1abT,
    unsigned short* __restrict__ P, unsigned short* __restrict__ Q, int Nn) {
  __shared__ unsigned short hs[64 * TS];
  const int tid = threadIdx.x;
  const int row0 = blockIdx.x * 64;
#pragma unroll
  for (int i = 0; i < 8; ++i) {
    int idx = tid + i * 256;
    int r = idx >> 5, c4 = (idx & 31) << 2;
    float4 v = make_float4(0.f, 0.f, 0.f, 0.f);
    if (row0 + r < Nn) v = *(const float4*)(h + (size_t)(row0 + r) * 128 + c4);
    *(uint2*)&hs[r * TS + c4] = make_uint2(pk2(v.x, v.y), pk2(v.z, v.w));
  }
  __syncthreads();
  const int lane = tid & 63, wv = tid >> 6;
  const int m16 = lane & 15, quad = lane >> 4;
  floatx4 acc[4][4];
#pragma unroll
  for (int mt = 0; mt < 4; ++mt)
#pragma unroll
    for (int nt = 0; nt < 4; ++nt) acc[mt][nt] = (floatx4)(0.0f);
  const __bf16* WT = (const __bf16*)W1abT;
  const __bf16* TlB = (const __bf16*)hs;
#pragma unroll
  for (int kb = 0; kb < 4; ++kb) {
    bf16x8 a[4], w[4];
#pragma unroll
    for (int mt = 0; mt < 4; ++mt)
      a[mt] = *(const bf16x8*)(TlB + (16 * mt + m16) * TS + kb * 32 + quad * 8);
#pragma unroll
    for (int nt = 0; nt < 4; ++nt)
      w[nt] = *(const bf16x8*)(WT + (size_t)(64 * wv + 16 * nt + m16) * 128 + kb * 32 + quad * 8);
#pragma unroll
    for (int mt = 0; mt < 4; ++mt)
#pragma unroll
      for (int nt = 0; nt < 4; ++nt)
        acc[mt][nt] = __builtin_amdgcn_mfma_f32_16x16x32_bf16(w[nt], a[mt], acc[mt][nt], 0, 0, 0);
  }
#pragma unroll
  for (int mt = 0; mt < 4; ++mt) {
    int row = row0 + 16 * mt + m16;
    if (row >= Nn) continue;
#pragma unroll
    for (int nt = 0; nt < 4; ++nt) {
      int n0 = 64 * wv + 16 * nt + 4 * quad;
      floatx4 A = acc[mt][nt];
      uint2 o = make_uint2(pk2(A[0], A[1]), pk2(A[2], A[3]));
      if (n0 < 128) *(uint2*)(P + (size_t)row * 128 + n0) = o;
      else *(uint2*)(Q + (size_t)row * 128 + (n0 - 128)) = o;
    }
  }
}

// ---------------- edge kernel helpers ----------------
static __device__ __forceinline__ void gather_pq(
    const unsigned short* __restrict__ P, const unsigned short* __restrict__ Q,
    const int* __restrict__ sdstBase, const int* __restrict__ ssrcBase,
    int rw, int c0, uint4* pv, uint4* qv) {
#pragma unroll
  for (int p = 0; p < 4; ++p) {
    int slot = 16 * p + rw;
    int dn = sdstBase[slot];
    int dna = dn < 0 ? 0 : dn;
    int sna = ssrcBase[slot];
    pv[p] = *(const uint4*)(P + (size_t)dna * 128 + c0);
    qv[p] = *(const uint4*)(Q + (size_t)sna * 128 + c0);
  }
}

static __device__ __forceinline__ void build_T(
    unsigned short* __restrict__ TlBuf,
    const uint4* pv, const uint4* qv,
    const int* __restrict__ sdstBase, const float* __restrict__ seaBase,
    const float wc[4][8], const float b1r[8], int rw, int c0) {
#pragma unroll
  for (int p = 0; p < 4; ++p) {
    int row = 16 * p + rw;
    int dn = sdstBase[row];
    uint4 out = make_uint4(0u, 0u, 0u, 0u);
    if (dn >= 0) {
      float e0f = seaBase[row * 4 + 0], e1f = seaBase[row * 4 + 1];
      float e2f = seaBase[row * 4 + 2], e3f = seaBase[row * 4 + 3];
      unsigned pu[4] = {pv[p].x, pv[p].y, pv[p].z, pv[p].w};
      unsigned qu[4] = {qv[p].x, qv[p].y, qv[p].z, qv[p].w};
      unsigned ou[4];
#pragma unroll
      for (int g = 0; g < 4; ++g) {
        float plo = ubits(pu[g] << 16), phi = ubits(pu[g] & 0xffff0000u);
        float qlo = ubits(qu[g] << 16), qhi = ubits(qu[g] & 0xffff0000u);
        int j0 = 2 * g, j1 = 2 * g + 1;
        float t0 = plo + qlo + b1r[j0];
        float t1 = phi + qhi + b1r[j1];
        t0 = fmaf(e0f, wc[0][j0], fmaf(e1f, wc[1][j0], fmaf(e2f, wc[2][j0], fmaf(e3f, wc[3][j0], t0))));
        t1 = fmaf(e0f, wc[0][j1], fmaf(e1f, wc[1][j1], fmaf(e2f, wc[2][j1], fmaf(e3f, wc[3][j1], t1))));
        ou[g] = pk2(fmaxf(t0, 0.f), fmaxf(t1, 0.f));
      }
      out = make_uint4(ou[0], ou[1], ou[2], ou[3]);
    }
    *(uint4*)&TlBuf[row * TS + c0] = out;
  }
}

static __device__ __forceinline__ void mfma_B(
    const unsigned short* __restrict__ TlBuf, const __bf16* __restrict__ WT,
    int m16, int quad, int wv, floatx4 acc[4][2]) {
#pragma unroll
  for (int mt = 0; mt < 4; ++mt) { acc[mt][0] = (floatx4)(0.0f); acc[mt][1] = (floatx4)(0.0f); }
  const __bf16* TlB = (const __bf16*)TlBuf;
#pragma unroll
  for (int kb = 0; kb < 4; ++kb) {
    bf16x8 w0 = *(const bf16x8*)(WT + (size_t)(32 * wv + m16) * 128 + kb * 32 + quad * 8);
    bf16x8 w1 = *(const bf16x8*)(WT + (size_t)(32 * wv + 16 + m16) * 128 + kb * 32 + quad * 8);
    bf16x8 a[4];
#pragma unroll
    for (int mt = 0; mt < 4; ++mt)
      a[mt] = *(const bf16x8*)(TlB + (16 * mt + m16) * TS + kb * 32 + quad * 8);
#pragma unroll
    for (int mt = 0; mt < 4; ++mt) {
      acc[mt][0] = __builtin_amdgcn_mfma_f32_16x16x32_bf16(w0, a[mt], acc[mt][0], 0, 0, 0);
      acc[mt][1] = __builtin_amdgcn_mfma_f32_16x16x32_bf16(w1, a[mt], acc[mt][1], 0, 0, 0);
    }
  }
}

static __device__ __forceinline__ void epi_m(
    unsigned short* __restrict__ TlBuf, floatx4 acc[4][2],
    const float* __restrict__ B2f, int m16, int quad, int wv) {
  int n0 = 32 * wv + 4 * quad;
  float4 bv0 = *(const float4*)(B2f + n0);
  float4 bv1 = *(const float4*)(B2f + n0 + 16);
#pragma unroll
  for (int mt = 0; mt < 4; ++mt) {
    int row = 16 * mt + m16;
    floatx4 A0 = acc[mt][0], A1 = acc[mt][1];
    *(uint2*)&TlBuf[row * TS + n0] =
        make_uint2(pk2(fmaxf(A0[0] + bv0.x, 0.f), fmaxf(A0[1] + bv0.y, 0.f)),
                   pk2(fmaxf(A0[2] + bv0.z, 0.f), fmaxf(A0[3] + bv0.w, 0.f)));
    *(uint2*)&TlBuf[row * TS + n0 + 16] =
        make_uint2(pk2(fmaxf(A1[0] + bv1.x, 0.f), fmaxf(A1[1] + bv1.y, 0.f)),
                   pk2(fmaxf(A1[2] + bv1.z, 0.f), fmaxf(A1[3] + bv1.w, 0.f)));
  }
}

// mask-driven segmented reduce; thread covers cols c4..c4+3 and 64+c4..64+c4+3
// -> each store across the 16 participating consecutive lanes is 256 B contiguous.
static __device__ __forceinline__ void seg_reduce(
    const unsigned short* __restrict__ TlBuf, const int* __restrict__ sdstBase,
    unsigned long long mask, float* __restrict__ aggr, int tid) {
  const int c4 = (tid & 15) << 2;
  const int st = tid >> 4;
  const int dfirst = sdstBase[0], dlast = sdstBase[63];
  for (int s = st; s < 64; s += 16) {
    if (!(mask & (1ull << s))) continue;
    int dn = sdstBase[s];
    if (dn < 0) continue;
    int end;
    if (s >= 63) end = 64;
    else {
      unsigned long long m2 = mask >> (s + 1);
      end = m2 ? (s + 1 + (int)__builtin_ctzll(m2)) : 64;
    }
    float a0 = 0.f, a1 = 0.f, a2 = 0.f, a3 = 0.f, a4 = 0.f, a5 = 0.f, a6 = 0.f, a7 = 0.f;
    for (int e = s; e < end; ++e) {
      uint2 v1 = *(const uint2*)&TlBuf[e * TS + c4];
      uint2 v2 = *(const uint2*)&TlBuf[e * TS + 64 + c4];
      a0 += ubits(v1.x << 16); a1 += ubits(v1.x & 0xffff0000u);
      a2 += ubits(v1.y << 16); a3 += ubits(v1.y & 0xffff0000u);
      a4 += ubits(v2.x << 16); a5 += ubits(v2.x & 0xffff0000u);
      a6 += ubits(v2.y << 16); a7 += ubits(v2.y & 0xffff0000u);
    }
    float* ap = aggr + (size_t)dn * 128 + c4;
    if (dn == dfirst || dn == dlast) {
      atomicAdd(ap + 0, a0); atomicAdd(ap + 1, a1);
      atomicAdd(ap + 2, a2); atomicAdd(ap + 3, a3);
      atomicAdd(ap + 64, a4); atomicAdd(ap + 65, a5);
      atomicAdd(ap + 66, a6); atomicAdd(ap + 67, a7);
    } else {
      *(float4*)ap = make_float4(a0, a1, a2, a3);
      *(float4*)(ap + 64) = make_float4(a4, a5, a6, a7);
    }
  }
}

// ---------------- edge message kernel: 2 tiles/block, pipelined, XCD-swizzled ----------------
__global__ __launch_bounds__(256, 3) void edge_kernel(
    const unsigned short* __restrict__ P, const unsigned short* __restrict__ Q,
    const float* __restrict__ ea_s, const int* __restrict__ dst_s, const int* __restrict__ src_s,
    const unsigned long long* __restrict__ masks,
    const float* __restrict__ W1c, const float* __restrict__ b1,
    const unsigned short* __restrict__ W2fT, const float* __restrict__ B2f,
    float* __restrict__ aggr, int Ee, int nT) {
  __shared__ unsigned short Tl[2][64 * TS];
  __shared__ float sea[128 * 4];
  __shared__ int sdst[128], ssrc[128];
  const int tid = threadIdx.x;
  // XCD swizzle: blocks round-robin over 8 XCDs; give each XCD a contiguous
  // range of edge tiles (perf heuristic only — any mapping is correct).
  int b = blockIdx.x;
  const int nB = gridDim.x;
  const int per = nB >> 3;
  if (b < (per << 3)) b = (b & 7) * per + (b >> 3);
  const int t0 = b * 2, t1 = t0 + 1;
  const int e0 = t0 * 64;
  const bool has1 = (t1 < nT);
  const unsigned long long mask0 = masks[t0];
  const unsigned long long mask1 = has1 ? masks[t1] : 0ull;
  if (tid < 128) {
    int e = e0 + tid;
    bool ok = e < Ee;
    sdst[tid] = ok ? dst_s[e] : -1;
    ssrc[tid] = ok ? src_s[e] : 0;
    float4 ev = ok ? *(const float4*)(ea_s + (size_t)e * 4) : make_float4(0.f, 0.f, 0.f, 0.f);
    *(float4*)&sea[tid * 4] = ev;
  }
  // per-thread W1c slice: cols c0..c0+7
  const int rw = tid >> 4, c0 = (tid & 15) << 3;
  float wc[4][8], b1r[8];
#pragma unroll
  for (int r = 0; r < 4; ++r) {
    *(float4*)&wc[r][0] = *(const float4*)(W1c + r * 128 + c0);
    *(float4*)&wc[r][4] = *(const float4*)(W1c + r * 128 + c0 + 4);
  }
  *(float4*)&b1r[0] = *(const float4*)(b1 + c0);
  *(float4*)&b1r[4] = *(const float4*)(b1 + c0 + 4);
  __syncthreads();

  const int lane = tid & 63, wv = tid >> 6;
  const int m16 = lane & 15, quad = lane >> 4;
  const __bf16* WT = (const __bf16*)W2fT;

  // --- pipeline ---
  uint4 pv[4], qv[4], pv1[4], qv1[4];
  gather_pq(P, Q, sdst, ssrc, rw, c0, pv, qv);                 // tile0 gathers
  build_T(Tl[0], pv, qv, sdst, sea, wc, b1r, rw, c0);          // T0 -> Tl[0]
  if (has1) gather_pq(P, Q, sdst + 64, ssrc + 64, rw, c0, pv1, qv1);  // tile1 gathers in flight
  __syncthreads();                                             // Tl[0] ready

  floatx4 acc[4][2];
  mfma_B(Tl[0], WT, m16, quad, wv, acc);                       // B0 (reads Tl[0])
  if (has1) build_T(Tl[1], pv1, qv1, sdst + 64, sea + 256, wc, b1r, rw, c0);  // T1 -> Tl[1]
  __syncthreads();                                             // B0 reads done; Tl[1] ready

  epi_m(Tl[0], acc, B2f, m16, quad, wv);                       // m0 -> Tl[0]
  floatx4 acc1[4][2];
  if (has1) mfma_B(Tl[1], WT, m16, quad, wv, acc1);            // B1 (reads Tl[1])
  __syncthreads();                                             // m0 ready; B1 reads done

  seg_reduce(Tl[0], sdst, mask0, aggr, tid);                   // C0
  if (has1) {
    epi_m(Tl[1], acc1, B2f, m16, quad, wv);                    // m1 -> Tl[1]
    __syncthreads();                                           // m1 ready
    seg_reduce(Tl[1], sdst + 64, mask1, aggr, tid);            // C1
  }
}

// ---------------- fused update MLP (+ next-layer P/Q), MFMA, in-place h ----------------
__global__ __launch_bounds__(256) void upd_kernel(
    float* __restrict__ h, const float* __restrict__ aggr,
    const unsigned short* __restrict__ U1T, const float* __restrict__ ub1,
    const unsigned short* __restrict__ uW2fT, const float* __restrict__ uB2f, int Nn,
    const unsigned short* __restrict__ W1abT_next,
    unsigned short* __restrict__ P, unsigned short* __restrict__ Q) {
  __shared__ unsigned short as_[64 * AS];  // [h|aggr]; u1 overlay; then h_new overlay
  const int tid = threadIdx.x;
  const int row0 = blockIdx.x * 64;
#pragma unroll
  for (int i = 0; i < 8; ++i) {
    int idx = tid + i * 256;
    int r = idx >> 5, c4 = (idx & 31) << 2;
    float4 v = make_float4(0.f, 0.f, 0.f, 0.f);
    if (row0 + r < Nn) v = *(const float4*)(h + (size_t)(row0 + r) * 128 + c4);
    *(uint2*)&as_[r * AS + c4] = make_uint2(pk2(v.x, v.y), pk2(v.z, v.w));
  }
#pragma unroll
  for (int i = 0; i < 8; ++i) {
    int idx = tid + i * 256;
    int r = idx >> 5, c4 = (idx & 31) << 2;
    float4 v = make_float4(0.f, 0.f, 0.f, 0.f);
    if (row0 + r < Nn) v = *(const float4*)(aggr + (size_t)(row0 + r) * 128 + c4);
    *(uint2*)&as_[r * AS + 128 + c4] = make_uint2(pk2(v.x, v.y), pk2(v.z, v.w));
  }
  __syncthreads();
  const int lane = tid & 63, wv = tid >> 6;
  const int m16 = lane & 15, quad = lane >> 4;
  const __bf16* asB = (const __bf16*)as_;
  unsigned short* u1s = as_;  // overlay (TS stride)
  // pass 1: u1 = relu([h|aggr]@U1 + ub1), K=256
  {
    floatx4 acc[4][2];
#pragma unroll
    for (int mt = 0; mt < 4; ++mt) { acc[mt][0] = (floatx4)(0.0f); acc[mt][1] = (floatx4)(0.0f); }
    const __bf16* WT = (const __bf16*)U1T;
#pragma unroll
    for (int kb = 0; kb < 8; ++kb) {
      bf16x8 w0 = *(const bf16x8*)(WT + (size_t)(32 * wv + m16) * 256 + kb * 32 + quad * 8);
      bf16x8 w1 = *(const bf16x8*)(WT + (size_t)(32 * wv + 16 + m16) * 256 + kb * 32 + quad * 8);
      bf16x8 a[4];
#pragma unroll
      for (int mt = 0; mt < 4; ++mt)
        a[mt] = *(const bf16x8*)(asB + (16 * mt + m16) * AS + kb * 32 + quad * 8);
#pragma unroll
      for (int mt = 0; mt < 4; ++mt) {
        acc[mt][0] = __builtin_amdgcn_mfma_f32_16x16x32_bf16(w0, a[mt], acc[mt][0], 0, 0, 0);
        acc[mt][1] = __builtin_amdgcn_mfma_f32_16x16x32_bf16(w1, a[mt], acc[mt][1], 0, 0, 0);
      }
    }
    __syncthreads();  // pass-1 reads of as_ complete -> safe to overlay u1
    int n0 = 32 * wv + 4 * quad;
    float4 bv0 = *(const float4*)(ub1 + n0);
    float4 bv1 = *(const float4*)(ub1 + n0 + 16);
#pragma unroll
    for (int mt = 0; mt < 4; ++mt) {
      int row = 16 * mt + m16;
      floatx4 A0 = acc[mt][0], A1 = acc[mt][1];
      *(uint2*)&u1s[row * TS + n0] =
          make_uint2(pk2(fmaxf(A0[0] + bv0.x, 0.f), fmaxf(A0[1] + bv0.y, 0.f)),
                     pk2(fmaxf(A0[2] + bv0.z, 0.f), fmaxf(A0[3] + bv0.w, 0.f)));
      *(uint2*)&u1s[row * TS + n0 + 16] =
          make_uint2(pk2(fmaxf(A1[0] + bv1.x, 0.f), fmaxf(A1[1] + bv1.y, 0.f)),
                     pk2(fmaxf(A1[2] + bv1.z, 0.f), fmaxf(A1[3] + bv1.w, 0.f)));
    }
  }
  __syncthreads();
  // pass 2: h_new = h + relu(u1@U2f + uB2f), K=128; write global + LDS bf16
  {
    floatx4 acc[4][2];
#pragma unroll
    for (int mt = 0; mt < 4; ++mt) { acc[mt][0] = (floatx4)(0.0f); acc[mt][1] = (floatx4)(0.0f); }
    const __bf16* WT = (const __bf16*)uW2fT;
    const __bf16* u1B = (const __bf16*)u1s;
#pragma unroll
    for (int kb = 0; kb < 4; ++kb) {
      bf16x8 w0 = *(const bf16x8*)(WT + (size_t)(32 * wv + m16) * 128 + kb * 32 + quad * 8);
      bf16x8 w1 = *(const bf16x8*)(WT + (size_t)(32 * wv + 16 + m16) * 128 + kb * 32 + quad * 8);
      bf16x8 a[4];
#pragma unroll
      for (int mt = 0; mt < 4; ++mt)
        a[mt] = *(const bf16x8*)(u1B + (16 * mt + m16) * TS + kb * 32 + quad * 8);
#pragma unroll
      for (int mt = 0; mt < 4; ++mt) {
        acc[mt][0] = __builtin_amdgcn_mfma_f32_16x16x32_bf16(w0, a[mt], acc[mt][0], 0, 0, 0);
        acc[mt][1] = __builtin_amdgcn_mfma_f32_16x16x32_bf16(w1, a[mt], acc[mt][1], 0, 0, 0);
      }
    }
    __syncthreads();  // pass-2 reads of u1s complete -> safe to overlay h_new
    int n0 = 32 * wv + 4 * quad;
    float4 bv0 = *(const float4*)(uB2f + n0);
    float4 bv1 = *(const float4*)(uB2f + n0 + 16);
#pragma unroll
    for (int mt = 0; mt < 4; ++mt) {
      int rloc = 16 * mt + m16;
      int row = row0 + rloc;
      floatx4 A0 = acc[mt][0], A1 = acc[mt][1];
      if (row < Nn) {
        float* hp0 = h + (size_t)row * 128 + n0;
        float4 hv0 = *(float4*)hp0;
        float4 o0 = make_float4(hv0.x + fmaxf(A0[0] + bv0.x, 0.f), hv0.y + fmaxf(A0[1] + bv0.y, 0.f),
                                hv0.z + fmaxf(A0[2] + bv0.z, 0.f), hv0.w + fmaxf(A0[3] + bv0.w, 0.f));
        *(float4*)hp0 = o0;
        float* hp1 = hp0 + 16;
        float4 hv1 = *(float4*)hp1;
        float4 o1 = make_float4(hv1.x + fmaxf(A1[0] + bv1.x, 0.f), hv1.y + fmaxf(A1[1] + bv1.y, 0.f),
                                hv1.z + fmaxf(A1[2] + bv1.z, 0.f), hv1.w + fmaxf(A1[3] + bv1.w, 0.f));
        *(float4*)hp1 = o1;
        if (W1abT_next) {
          *(uint2*)&u1s[rloc * TS + n0] = make_uint2(pk2(o0.x, o0.y), pk2(o0.z, o0.w));
          *(uint2*)&u1s[rloc * TS + n0 + 16] = make_uint2(pk2(o1.x, o1.y), pk2(o1.z, o1.w));
        }
      } else if (W1abT_next) {
        *(uint2*)&u1s[rloc * TS + n0] = make_uint2(0u, 0u);
        *(uint2*)&u1s[rloc * TS + n0 + 16] = make_uint2(0u, 0u);
      }
    }
  }
  // fused next-layer P/Q from h_new tile in LDS
  if (W1abT_next) {
    __syncthreads();
    floatx4 pacc[4][4];
#pragma unroll
    for (int mt = 0; mt < 4; ++mt)
#pragma unroll
      for (int nt = 0; nt < 4; ++nt) pacc[mt][nt] = (floatx4)(0.0f);
    const __bf16* WT = (const __bf16*)W1abT_next;
    const __bf16* hB = (const __bf16*)u1s;
#pragma unroll
    for (int kb = 0; kb < 4; ++kb) {
      bf16x8 a[4], w[4];
#pragma unroll
      for (int mt = 0; mt < 4; ++mt)
        a[mt] = *(const bf16x8*)(hB + (16 * mt + m16) * TS + kb * 32 + quad * 8);
#pragma unroll
      for (int nt = 0; nt < 4; ++nt)
        w[nt] = *(const bf16x8*)(WT + (size_t)(64 * wv + 16 * nt + m16) * 128 + kb * 32 + quad * 8);
#pragma unroll
      for (int mt = 0; mt < 4; ++mt)
#pragma unroll
        for (int nt = 0; nt < 4; ++nt)
          pacc[mt][nt] = __builtin_amdgcn_mfma_f32_16x16x32_bf16(w[nt], a[mt], pacc[mt][nt], 0, 0, 0);
    }
#pragma unroll
    for (int mt = 0; mt < 4; ++mt) {
      int row = row0 + 16 * mt + m16;
      if (row >= Nn) continue;
#pragma unroll
      for (int nt = 0; nt < 4; ++nt) {
        int n0 = 64 * wv + 16 * nt + 4 * quad;
        floatx4 A = pacc[mt][nt];
        uint2 o = make_uint2(pk2(A[0], A[1]), pk2(A[2], A[3]));
        if (n0 < 128) *(uint2*)(P + (size_t)row * 128 + n0) = o;
        else *(uint2*)(Q + (size_t)row * 128 + (n0 - 128)) = o;
      }
    }
  }
}

// ---------------- pooling ----------------
__global__ __launch_bounds__(128) void pool_sum_kernel(
    const float* __restrict__ h, const int* __restrict__ batch,
    float* __restrict__ sums, int* __restrict__ gcnt, int Nn) {
  int n0 = blockIdx.x * 256;
  if (n0 >= Nn) return;
  int nend = min(n0 + 256, Nn);
  int d = threadIdx.x;
  int gcur = batch[n0];
  float run = 0.f;
  int cnt = 0;
  for (int n = n0; n < nend; ++n) {
    int g = batch[n];
    if (g != gcur) {
      atomicAdd(&sums[(size_t)gcur * 128 + d], run);
      if (d == 0) atomicAdd(&gcnt[gcur], cnt);
      run = 0.f; cnt = 0; gcur = g;
    }
    run += h[(size_t)n * 128 + d];
    cnt += 1;
  }
  atomicAdd(&sums[(size_t)gcur * 128 + d], run);
  if (d == 0) atomicAdd(&gcnt[gcur], cnt);
}

__global__ __launch_bounds__(128) void pred_kernel(
    const float* __restrict__ sums, const int* __restrict__ gcnt,
    const float* __restrict__ pw, const float* __restrict__ pb, float* __restrict__ out) {
  __shared__ float red[2];
  int g = blockIdx.x, d = threadIdx.x;
  float c = fmaxf((float)gcnt[g], 1.f);
  float v = (sums[(size_t)g * 128 + d] / c) * pw[d];
  for (int o = 32; o > 0; o >>= 1) v += __shfl_down(v, o, 64);
  if ((d & 63) == 0) red[d >> 6] = v;
  __syncthreads();
  if (d == 0) out[g] = red[0] + red[1] + pb[0];
}

// ---------------- launch ----------------
extern "C" void kernel_launch(void* const* d_in, const int* in_sizes, int n_in,
                              void* d_out, int out_size, void* d_ws, size_t ws_size,
                              hipStream_t stream) {
  const float* x = (const float*)d_in[0];
  const float* pos = (const float*)d_in[1];
  const int* ei = (const int*)d_in[2];
  const float* ea = (const float*)d_in[3];
  const int* batch = (const int*)d_in[4];
  const float* lin_w = (const float*)d_in[5];
  const float* lin_b = (const float*)d_in[6];
  const float* mw1 = (const float*)d_in[7];
  const float* mb1 = (const float*)d_in[8];
  const float* mg = (const float*)d_in[9];
  const float* mbb = (const float*)d_in[10];
  const float* mm = (const float*)d_in[11];
  const float* mv = (const float*)d_in[12];
  const float* mw2 = (const float*)d_in[13];
  const float* mb2 = (const float*)d_in[14];
  const float* uw1 = (const float*)d_in[15];
  const float* ub1 = (const float*)d_in[16];
  const float* ug = (const float*)d_in[17];
  const float* ubb = (const float*)d_in[18];
  const float* um = (const float*)d_in[19];
  const float* uv = (const float*)d_in[20];
  const float* uw2 = (const float*)d_in[21];
  const float* ub2 = (const float*)d_in[22];
  const float* pw = (const float*)d_in[23];
  const float* pb = (const float*)d_in[24];
  float* out = (float*)d_out;

  const int Nn = in_sizes[0] / 11;
  const int Ee = in_sizes[3] / 4;
  const int* srcp = ei;        // edge_index[0] = source j
  const int* dstp = ei + Ee;   // edge_index[1] = target i

  char* wsb = (char*)d_ws;
  size_t off = 0;
  auto alloc = [&](size_t bytes) -> void* {
    void* p = wsb + off;
    off = (off + bytes + 255) & ~(size_t)255;
    return p;
  };
  float* h = (float*)alloc((size_t)Nn * 128 * 4);
  unsigned short* Pb = (unsigned short*)alloc((size_t)Nn * 128 * 2);
  unsigned short* Qb = (unsigned short*)alloc((size_t)Nn * 128 * 2);
  float* aggr = (float*)alloc((size_t)Nn * 128 * 4);
  int* dst_s = (int*)alloc((size_t)Ee * 4);
  int* src_s = (int*)alloc((size_t)Ee * 4);
  float* ea_s = (float*)alloc((size_t)Ee * 16);
  int* count = (int*)alloc((size_t)Nn * 4);
  int* cursor = (int*)alloc((size_t)Nn * 4);
  int* bsum = (int*)alloc((size_t)1024 * 4);
  const int nTiles = (Ee + 63) / 64;
  unsigned long long* masks = (unsigned long long*)alloc((size_t)nTiles * 8);
  unsigned short* mW2fT = (unsigned short*)alloc((size_t)4 * 128 * 128 * 2);
  unsigned short* uW2fT = (unsigned short*)alloc((size_t)4 * 128 * 128 * 2);
  unsigned short* W1abT = (unsigned short*)alloc((size_t)4 * 256 * 128 * 2);
  unsigned short* U1T = (unsigned short*)alloc((size_t)4 * 128 * 256 * 2);
  float* mB2f = (float*)alloc((size_t)4 * 128 * 4);
  float* uB2f = (float*)alloc((size_t)4 * 128 * 4);
  float* sums = (float*)alloc((size_t)out_size * 128 * 4);
  int* gcnt = (int*)alloc((size_t)out_size * 4);
  (void)ws_size; (void)n_in;

  fold_kernel<<<8, 128, 0, stream>>>(mw2, mb2, mg, mbb, mm, mv,
                                     uw2, ub2, ug, ubb, um, uv,
                                     mW2fT, mB2f, uW2fT, uB2f);
  transp_kernel<<<8, 256, 0, stream>>>(mw1, uw1, W1abT, U1T);
  lin_in_kernel<<<(Nn * 128 + 255) / 256, 256, 0, stream>>>(x, pos, lin_w, lin_b, h, Nn);

  hipMemsetAsync(count, 0, (size_t)Nn * 4, stream);
  hist_kernel<<<(Ee + 255) / 256, 256, 0, stream>>>(dstp, count, Ee);
  const int NB = (Nn + 1023) / 1024;
  scan1_kernel<<<NB, 1024, 0, stream>>>(count, cursor, bsum, Nn);
  scan2_kernel<<<1, 1024, 0, stream>>>(bsum, NB);
  scan3_kernel<<<NB, 1024, 0, stream>>>(cursor, bsum, Nn);
  scatter_kernel<<<(Ee + 255) / 256, 256, 0, stream>>>(srcp, dstp, ea, cursor,
                                                       dst_s, src_s, ea_s, Ee);
  mask_kernel<<<(nTiles + 3) / 4, 256, 0, stream>>>(dst_s, masks, Ee, nTiles);

  const int gN = (Nn + 63) / 64;
  pq_kernel<<<gN, 256, 0, stream>>>(h, W1abT, Pb, Qb, Nn);  // layer 0 P/Q
  for (int l = 0; l < 4; ++l) {
    hipMemsetAsync(aggr, 0, (size_t)Nn * 128 * 4, stream);
    edge_kernel<<<(nTiles + 1) / 2, 256, 0, stream>>>(
        Pb, Qb, ea_s, dst_s, src_s, masks,
        mw1 + (size_t)l * 260 * 128 + 256 * 128, mb1 + l * 128,
        mW2fT + (size_t)l * 16384, mB2f + l * 128, aggr, Ee, nTiles);
    upd_kernel<<<gN, 256, 0, stream>>>(
        h, aggr, U1T + (size_t)l * 128 * 256, ub1 + l * 128,
        uW2fT + (size_t)l * 16384, uB2f + l * 128, Nn,
        (l < 3) ? (W1abT + (size_t)(l + 1) * 256 * 128) : nullptr, Pb, Qb);
  }

  hipMemsetAsync(sums, 0, (size_t)out_size * 128 * 4, stream);
  hipMemsetAsync(gcnt, 0, (size_t)out_size * 4, stream);
  pool_sum_kernel<<<(Nn + 255) / 256, 128, 0, stream>>>(h, batch, sums, gcnt, Nn);
  pred_kernel<<<out_size, 128, 0, stream>>>(sums, gcnt, pw, pb, out);
}